// Round 8
// baseline (210.660 us; speedup 1.0000x reference)
//
#include <hip/hip_runtime.h>
#include <math.h>

#define BB    512
#define NN    128
#define OBSD  128
#define MSGD  64
#define EHID  128
#define IHID  256

typedef __attribute__((ext_vector_type(8))) short          s16x8;
typedef __attribute__((ext_vector_type(4))) short          s16x4;
typedef __attribute__((ext_vector_type(8))) unsigned short u16x8;
typedef __attribute__((ext_vector_type(4))) unsigned short u16x4;
typedef __attribute__((ext_vector_type(4))) float          f32x4;

// native bf16 convert -> compiler emits v_cvt_pk_bf16_f32 (RNE), not bit-twiddle
__device__ __forceinline__ unsigned short f2bf(float f) {
    return __builtin_bit_cast(unsigned short, (__bf16)f);
}
__device__ __forceinline__ float bf2f(unsigned short b) {
    return (float)__builtin_bit_cast(__bf16, b);
}

#if defined(__has_builtin) && __has_builtin(__builtin_amdgcn_mfma_f32_16x16x16bf16_1k)
__device__ __forceinline__ f32x4 MFMA16(s16x4 a, s16x4 b, f32x4 c) {
    return __builtin_amdgcn_mfma_f32_16x16x16bf16_1k(a, b, c, 0, 0, 0);
}
#else
__device__ __forceinline__ f32x4 MFMA16(s16x4 a, s16x4 b, f32x4 c) {
    f32x4 d;
    asm volatile("v_mfma_f32_16x16x16_bf16 %0, %1, %2, %3\n\ts_nop 7\n\ts_nop 7"
                 : "=v"(d) : "v"(a), "v"(b), "v"(c));
    return d;
}
#endif

// ---------------------------------------------------------------------------
// prep1: fold linear layers (fp32). ws fp32 layout:
//   WqP@0, WkP@8192, WvP@16384, WfP@24576, bcat@40960, bfold@41216
// ---------------------------------------------------------------------------
__global__ __launch_bounds__(256) void k_prep1(
    const float* __restrict__ ew2, const float* __restrict__ eb2,
    const float* __restrict__ wq, const float* __restrict__ bq,
    const float* __restrict__ wk, const float* __restrict__ bk,
    const float* __restrict__ wv, const float* __restrict__ bv,
    const float* __restrict__ wo, const float* __restrict__ bo,
    const float* __restrict__ iw1, const float* __restrict__ ib1,
    float* __restrict__ wsf)
{
    int idx = blockIdx.x * 256 + threadIdx.x;
    if (idx >= 41472) return;
    if (idx < 24576) {
        const float* W = (idx < 8192) ? wq : (idx < 16384) ? wk : wv;
        int t = idx & 8191;
        int k = t >> 6, n = t & 63;
        float s = 0.0f;
        for (int m = 0; m < 64; ++m) s = fmaf(ew2[k * 64 + m], W[m * 64 + n], s);
        wsf[idx] = s;
    } else if (idx < 40960) {
        int t = idx - 24576;
        int k = t >> 8, n = t & 255;
        float s = 0.0f;
        for (int m = 0; m < 64; ++m) s = fmaf(wo[k * 64 + m], iw1[(128 + m) * 256 + n], s);
        wsf[idx] = s;
    } else if (idx < 41216) {
        int n = idx - 40960;
        float s;
        if (n < 64) s = eb2[n];
        else {
            int c = n & 63;
            const float* W = (n < 128) ? wq : (n < 192) ? wk : wv;
            const float* bb = (n < 128) ? bq : (n < 192) ? bk : bv;
            s = bb[c];
            for (int m = 0; m < 64; ++m) s = fmaf(eb2[m], W[m * 64 + c], s);
        }
        wsf[idx] = s;
    } else {
        int n = idx - 41216;
        float s = ib1[n];
        for (int m = 0; m < 64; ++m) s = fmaf(bo[m], iw1[(128 + m) * 256 + n], s);
        wsf[idx] = s;
    }
}

// ---------------------------------------------------------------------------
// prep2: swizzle weights into bf16 MFMA fragment-linear layout.
// frag[((kk*NT + nt)*64 + lane)*8 + j] = bf16(W[kk*32+(lane>>4)*8+j][nt*16+(lane&15)])
// ushort layout: ew1s@0(16384) wcats@16384(32768) iw1ts@49152(32768)
//   wfs@81920(16384) iw2s@98304(32768)
// ---------------------------------------------------------------------------
__global__ __launch_bounds__(512) void k_prep2(
    const float* __restrict__ ew1, const float* __restrict__ ew2,
    const float* __restrict__ iw1, const float* __restrict__ iw2,
    const float* __restrict__ wsf, unsigned short* __restrict__ wsu)
{
    int b = blockIdx.x, t = threadIdx.x;
    int l = t >> 3, j = t & 7;
    int c = l & 15, g = l >> 4;
    float v;
    unsigned short* dst;
    if (b < 32) {              // ew1s: K=128 N=128, NT=8
        int kk = b >> 3, nt = b & 7;
        int k = kk * 32 + g * 8 + j, n = nt * 16 + c;
        v = ew1[k * 128 + n];
        dst = wsu + b * 512;
    } else if (b < 96) {       // wcats: K=128 N=256 (ew2 | WqP | WkP | WvP)
        int tt = b - 32;
        int kk = tt >> 4, nt = tt & 15;
        int k = kk * 32 + g * 8 + j, n = nt * 16 + c;
        if (n < 64)       v = ew2[k * 64 + n];
        else if (n < 128) v = wsf[0     + k * 64 + (n - 64)];
        else if (n < 192) v = wsf[8192  + k * 64 + (n - 128)];
        else              v = wsf[16384 + k * 64 + (n - 192)];
        dst = wsu + 16384 + tt * 512;
    } else if (b < 160) {      // iw1ts: K=128 N=256 (top rows of iw1)
        int tt = b - 96;
        int kk = tt >> 4, nt = tt & 15;
        int k = kk * 32 + g * 8 + j, n = nt * 16 + c;
        v = iw1[k * 256 + n];
        dst = wsu + 49152 + tt * 512;
    } else if (b < 192) {      // wfs: K=64 N=256 (WfP)
        int tt = b - 160;
        int kk = tt >> 4, nt = tt & 15;
        int k = kk * 32 + g * 8 + j, n = nt * 16 + c;
        v = wsf[24576 + k * 256 + n];
        dst = wsu + 81920 + tt * 512;
    } else {                   // iw2s: K=256 N=128
        int tt = b - 192;
        int kk = tt >> 3, nt = tt & 7;
        int k = kk * 32 + g * 8 + j, n = nt * 16 + c;
        v = iw2[k * 128 + n];
        dst = wsu + 98304 + tt * 512;
    }
    dst[l * 8 + j] = f2bf(v);
}

// ---------------------------------------------------------------------------
// k_fused v2: one block = one batch (128 tokens), 512 threads = 8 waves (2Mx4N).
// Phases (10 barriers, LDS arena 51712 B -> 3 blocks/CU):
//   B: hid = relu(obs@ew1+eb1)        (obs read direct from global)
//   C: [msgs|q|k|vT] = hid@wcat+bcat  (msgs->global; q/k/vT overwrite hid)
//   D: attention (wave = head x query-half) -> ctxA
//   E: integrator GEMM1 (obs global + ctxA) + LN partials -> mu/rstd
//   F1/G1/F2/G2: split-K GEMM2 through a half-width (128-col) hid2 buffer
// Arena (ushort offsets): hid@0 s136 | q@0 s68, k@8704 s68, vT@17408 s132
//   | ctxA@0 s72, part(f32)@17408 | hid2h@0 s136
// ---------------------------------------------------------------------------
__global__ __launch_bounds__(512, 4) void k_fused(
    const float* __restrict__ obs,
    const unsigned short* __restrict__ ew1s, const float* __restrict__ eb1,
    const unsigned short* __restrict__ wcats, const float* __restrict__ bcat,
    float* __restrict__ msgs_out,
    const unsigned short* __restrict__ iw1ts, const unsigned short* __restrict__ wfs,
    const float* __restrict__ bfold, const float* __restrict__ lng,
    const float* __restrict__ lnb, const unsigned short* __restrict__ iw2s,
    const float* __restrict__ ib2, float* __restrict__ out)
{
    __shared__ unsigned short U[25856];          // 51712 B
    float* partp = (float*)&U[17408];            // [128][8] floats, alias

    const int tid = threadIdx.x, lane = tid & 63, w = tid >> 6;
    const int wm = w >> 2, wn = w & 3;           // M-half / N-quarter
    const int c15 = lane & 15, grp = lane >> 4;
    const long tok0 = (long)blockIdx.x * 128;
    const f32x4 zero = {0.f, 0.f, 0.f, 0.f};

    // ---- B: enc GEMM1: hid = relu(obs@ew1+eb1); obs A-frags from global
    {
        f32x4 a1[4][2];
        #pragma unroll
        for (int m = 0; m < 4; ++m) { a1[m][0] = zero; a1[m][1] = zero; }
        #pragma unroll
        for (int kk = 0; kk < 4; ++kk) {
            s16x8 b0 = *(const s16x8*)&ew1s[(((kk << 3) + 2 * wn + 0) * 64 + lane) * 8];
            s16x8 b1 = *(const s16x8*)&ew1s[(((kk << 3) + 2 * wn + 1) * 64 + lane) * 8];
            #pragma unroll
            for (int m = 0; m < 4; ++m) {
                const float* ap = obs + (tok0 + wm * 64 + m * 16 + c15) * OBSD + kk * 32 + grp * 8;
                float4 x0 = *(const float4*)ap;
                float4 x1 = *(const float4*)(ap + 4);
                s16x8 a;
                a[0] = f2bf(x0.x); a[1] = f2bf(x0.y); a[2] = f2bf(x0.z); a[3] = f2bf(x0.w);
                a[4] = f2bf(x1.x); a[5] = f2bf(x1.y); a[6] = f2bf(x1.z); a[7] = f2bf(x1.w);
                a1[m][0] = __builtin_amdgcn_mfma_f32_16x16x32_bf16(a, b0, a1[m][0], 0, 0, 0);
                a1[m][1] = __builtin_amdgcn_mfma_f32_16x16x32_bf16(a, b1, a1[m][1], 0, 0, 0);
            }
        }
        #pragma unroll
        for (int ntl = 0; ntl < 2; ++ntl) {
            int col = (2 * wn + ntl) * 16 + c15;
            float bias = eb1[col];
            #pragma unroll
            for (int m = 0; m < 4; ++m)
                #pragma unroll
                for (int r = 0; r < 4; ++r)
                    U[(wm * 64 + m * 16 + grp * 4 + r) * 136 + col] =
                        f2bf(fmaxf(a1[m][ntl][r] + bias, 0.f));
        }
    }
    __syncthreads();                                               // 1

    // ---- C: enc GEMM2: [msgs|q|k|v] = hid@wcat+bcat; wave owns N-quarter wn
    {
        f32x4 a2[4][4];
        #pragma unroll
        for (int m = 0; m < 4; ++m)
            #pragma unroll
            for (int n = 0; n < 4; ++n) a2[m][n] = zero;
        #pragma unroll
        for (int kk = 0; kk < 4; ++kk) {
            s16x8 b[4];
            #pragma unroll
            for (int ntl = 0; ntl < 4; ++ntl)
                b[ntl] = *(const s16x8*)&wcats[(((kk << 4) + 4 * wn + ntl) * 64 + lane) * 8];
            #pragma unroll
            for (int m = 0; m < 4; ++m) {
                s16x8 a = *(const s16x8*)&U[(wm * 64 + m * 16 + c15) * 136 + kk * 32 + grp * 8];
                #pragma unroll
                for (int ntl = 0; ntl < 4; ++ntl)
                    a2[m][ntl] = __builtin_amdgcn_mfma_f32_16x16x32_bf16(a, b[ntl], a2[m][ntl], 0, 0, 0);
            }
        }
        __syncthreads();                                           // 2 (hid dead)

        // wn==0 -> msgs (fp32 global); wn==1 -> q@0; wn==2 -> k@8704; wn==3 -> vT@17408
        #pragma unroll
        for (int ntl = 0; ntl < 4; ++ntl) {
            int lc = ntl * 16 + c15;
            float bias = bcat[wn * 64 + lc];
            #pragma unroll
            for (int m = 0; m < 4; ++m) {
                if (wn == 3) {
                    u16x4 o;
                    #pragma unroll
                    for (int r = 0; r < 4; ++r) o[r] = f2bf(a2[m][ntl][r] + bias);
                    *(u16x4*)&U[17408 + lc * 132 + wm * 64 + m * 16 + grp * 4] = o;
                } else {
                    #pragma unroll
                    for (int r = 0; r < 4; ++r) {
                        int t = wm * 64 + m * 16 + grp * 4 + r;
                        float v = a2[m][ntl][r] + bias;
                        if (wn == 0)      msgs_out[(tok0 + t) * MSGD + lc] = v;
                        else if (wn == 1) U[t * 68 + lc] = f2bf(v);
                        else              U[8704 + t * 68 + lc] = f2bf(v);
                    }
                }
            }
        }
    }
    __syncthreads();                                               // 3

    // ---- D: attention; wave = (query-half wm, head wn)
    {
        s16x4 akf[8], avf[8];
        #pragma unroll
        for (int kt = 0; kt < 8; ++kt) {
            akf[kt] = *(const s16x4*)&U[8704 + (kt * 16 + c15) * 68 + wn * 16 + grp * 4];
            avf[kt] = *(const s16x4*)&U[17408 + (wn * 16 + c15) * 132 + kt * 16 + grp * 4];
        }
        f32x4 oacc[4];
        float il[4];
        #pragma unroll
        for (int qt = 0; qt < 4; ++qt) {
            s16x4 qf = *(const s16x4*)&U[(wm * 64 + qt * 16 + c15) * 68 + wn * 16 + grp * 4];
            f32x4 s8[8];
            #pragma unroll
            for (int kt = 0; kt < 8; ++kt) s8[kt] = MFMA16(akf[kt], qf, zero);
            float mx = -1e30f;
            #pragma unroll
            for (int kt = 0; kt < 8; ++kt)
                #pragma unroll
                for (int r = 0; r < 4; ++r) mx = fmaxf(mx, s8[kt][r]);
            mx = fmaxf(mx, __shfl_xor(mx, 16, 64));
            mx = fmaxf(mx, __shfl_xor(mx, 32, 64));
            float l = 0.f;
            #pragma unroll
            for (int kt = 0; kt < 8; ++kt)
                #pragma unroll
                for (int r = 0; r < 4; ++r) {
                    float e = __expf((s8[kt][r] - mx) * 0.25f);
                    s8[kt][r] = e;
                    l += e;
                }
            l += __shfl_xor(l, 16, 64);
            l += __shfl_xor(l, 32, 64);
            il[qt] = 1.0f / l;
            oacc[qt] = zero;
            #pragma unroll
            for (int kt = 0; kt < 8; ++kt) {
                s16x4 pb;
                #pragma unroll
                for (int r = 0; r < 4; ++r) pb[r] = (short)f2bf(s8[kt][r]);
                oacc[qt] = MFMA16(avf[kt], pb, oacc[qt]);
            }
        }
        __syncthreads();                                           // 4 (q/k/vT dead)

        #pragma unroll
        for (int qt = 0; qt < 4; ++qt) {
            u16x4 o;
            #pragma unroll
            for (int r = 0; r < 4; ++r) o[r] = f2bf(oacc[qt][r] * il[qt]);
            *(u16x4*)&U[(wm * 64 + qt * 16 + c15) * 72 + wn * 16 + grp * 4] = o;
        }
    }
    __syncthreads();                                               // 5

    // ---- E: integrator GEMM1 + LN; wave owns tiles {h*8+2wn, h*8+2wn+1}, h=0,1
    f32x4 ai[4][2][2];                       // [m][half][ntl]
    {
        #pragma unroll
        for (int m = 0; m < 4; ++m)
            #pragma unroll
            for (int h = 0; h < 2; ++h)
                #pragma unroll
                for (int n = 0; n < 2; ++n) ai[m][h][n] = zero;
        #pragma unroll
        for (int kk = 0; kk < 4; ++kk) {
            s16x8 b[2][2];
            #pragma unroll
            for (int h = 0; h < 2; ++h)
                #pragma unroll
                for (int ntl = 0; ntl < 2; ++ntl)
                    b[h][ntl] = *(const s16x8*)&iw1ts[(((kk << 4) + h * 8 + 2 * wn + ntl) * 64 + lane) * 8];
            #pragma unroll
            for (int m = 0; m < 4; ++m) {
                const float* ap = obs + (tok0 + wm * 64 + m * 16 + c15) * OBSD + kk * 32 + grp * 8;
                float4 x0 = *(const float4*)ap;
                float4 x1 = *(const float4*)(ap + 4);
                s16x8 a;
                a[0] = f2bf(x0.x); a[1] = f2bf(x0.y); a[2] = f2bf(x0.z); a[3] = f2bf(x0.w);
                a[4] = f2bf(x1.x); a[5] = f2bf(x1.y); a[6] = f2bf(x1.z); a[7] = f2bf(x1.w);
                #pragma unroll
                for (int h = 0; h < 2; ++h)
                    #pragma unroll
                    for (int ntl = 0; ntl < 2; ++ntl)
                        ai[m][h][ntl] = __builtin_amdgcn_mfma_f32_16x16x32_bf16(a, b[h][ntl], ai[m][h][ntl], 0, 0, 0);
            }
        }
        #pragma unroll
        for (int kk = 0; kk < 2; ++kk) {
            s16x8 b[2][2];
            #pragma unroll
            for (int h = 0; h < 2; ++h)
                #pragma unroll
                for (int ntl = 0; ntl < 2; ++ntl)
                    b[h][ntl] = *(const s16x8*)&wfs[(((kk << 4) + h * 8 + 2 * wn + ntl) * 64 + lane) * 8];
            #pragma unroll
            for (int m = 0; m < 4; ++m) {
                s16x8 a = *(const s16x8*)&U[(wm * 64 + m * 16 + c15) * 72 + kk * 32 + grp * 8];
                #pragma unroll
                for (int h = 0; h < 2; ++h)
                    #pragma unroll
                    for (int ntl = 0; ntl < 2; ++ntl)
                        ai[m][h][ntl] = __builtin_amdgcn_mfma_f32_16x16x32_bf16(a, b[h][ntl], ai[m][h][ntl], 0, 0, 0);
            }
        }

        float bias[2][2];
        #pragma unroll
        for (int h = 0; h < 2; ++h)
            #pragma unroll
            for (int ntl = 0; ntl < 2; ++ntl)
                bias[h][ntl] = bfold[(h * 8 + 2 * wn + ntl) * 16 + c15];
        #pragma unroll
        for (int m = 0; m < 4; ++m) {
            #pragma unroll
            for (int r = 0; r < 4; ++r) {
                float s = 0.f, s2 = 0.f;
                #pragma unroll
                for (int h = 0; h < 2; ++h)
                    #pragma unroll
                    for (int ntl = 0; ntl < 2; ++ntl) {
                        float v = ai[m][h][ntl][r] + bias[h][ntl];
                        ai[m][h][ntl][r] = v;
                        s += v;
                        s2 = fmaf(v, v, s2);
                    }
                #pragma unroll
                for (int msk = 1; msk < 16; msk <<= 1) {
                    s  += __shfl_xor(s,  msk, 64);
                    s2 += __shfl_xor(s2, msk, 64);
                }
                if (c15 == 0)
                    *(float2*)&partp[(wm * 64 + m * 16 + grp * 4 + r) * 8 + 2 * wn] = make_float2(s, s2);
            }
        }
    }
    __syncthreads();                                               // 6 (ctxA dead)

    if (tid < 128) {
        float4 p0 = *(const float4*)&partp[tid * 8];
        float4 p1 = *(const float4*)&partp[tid * 8 + 4];
        float s  = p0.x + p0.z + p1.x + p1.z;
        float s2 = p0.y + p0.w + p1.y + p1.w;
        float mu = s * (1.0f / IHID);
        float var = s2 * (1.0f / IHID) - mu * mu;
        *(float2*)&partp[tid * 8] = make_float2(mu, rsqrtf(var + 1e-5f));
    }
    __syncthreads();                                               // 7

    // ---- F/G: LN-apply + split-K GEMM2 through half-width hid2 buffer
    f32x4 a3[4][2];
    #pragma unroll
    for (int m = 0; m < 4; ++m) { a3[m][0] = zero; a3[m][1] = zero; }

    #pragma unroll
    for (int h = 0; h < 2; ++h) {
        // F(h): apply LN+relu on this wave's half-h cols -> hid2h local cols
        float gg[2], bb[2];
        #pragma unroll
        for (int ntl = 0; ntl < 2; ++ntl) {
            int col = (h * 8 + 2 * wn + ntl) * 16 + c15;
            gg[ntl] = lng[col];
            bb[ntl] = lnb[col];
        }
        #pragma unroll
        for (int m = 0; m < 4; ++m)
            #pragma unroll
            for (int r = 0; r < 4; ++r) {
                int t = wm * 64 + m * 16 + grp * 4 + r;
                float2 mr = *(const float2*)&partp[t * 8];
                #pragma unroll
                for (int ntl = 0; ntl < 2; ++ntl) {
                    float v = fmaf((ai[m][h][ntl][r] - mr.x) * mr.y, gg[ntl], bb[ntl]);
                    U[t * 136 + (2 * wn + ntl) * 16 + c15] = f2bf(fmaxf(v, 0.f));
                }
            }
        __syncthreads();                                           // 8 / 10

        // G(h): accumulate out over k-half h (global kk = h*4 + kk)
        #pragma unroll
        for (int kk = 0; kk < 4; ++kk) {
            int gkk = h * 4 + kk;
            s16x8 b0 = *(const s16x8*)&iw2s[(((gkk << 3) + 2 * wn + 0) * 64 + lane) * 8];
            s16x8 b1 = *(const s16x8*)&iw2s[(((gkk << 3) + 2 * wn + 1) * 64 + lane) * 8];
            #pragma unroll
            for (int m = 0; m < 4; ++m) {
                s16x8 a = *(const s16x8*)&U[(wm * 64 + m * 16 + c15) * 136 + kk * 32 + grp * 8];
                a3[m][0] = __builtin_amdgcn_mfma_f32_16x16x32_bf16(a, b0, a3[m][0], 0, 0, 0);
                a3[m][1] = __builtin_amdgcn_mfma_f32_16x16x32_bf16(a, b1, a3[m][1], 0, 0, 0);
            }
        }
        if (h == 0) __syncthreads();                               // 9 (hid2h reads done)
    }

    #pragma unroll
    for (int ntl = 0; ntl < 2; ++ntl) {
        int col = (2 * wn + ntl) * 16 + c15;
        float bias2 = ib2[col];
        #pragma unroll
        for (int m = 0; m < 4; ++m)
            #pragma unroll
            for (int r = 0; r < 4; ++r)
                out[(tok0 + wm * 64 + m * 16 + grp * 4 + r) * OBSD + col] =
                    a3[m][ntl][r] + bias2;
    }
}

// ---------------------------------------------------------------------------
extern "C" void kernel_launch(void* const* d_in, const int* in_sizes, int n_in,
                              void* d_out, int out_size, void* d_ws, size_t ws_size,
                              hipStream_t stream)
{
    (void)in_sizes; (void)n_in; (void)out_size; (void)ws_size;

    const float* obs = (const float*)d_in[0];
    const float* ew1 = (const float*)d_in[1];
    const float* eb1 = (const float*)d_in[2];
    const float* ew2 = (const float*)d_in[3];
    const float* eb2 = (const float*)d_in[4];
    const float* wq  = (const float*)d_in[5];
    const float* bq  = (const float*)d_in[6];
    const float* wk  = (const float*)d_in[7];
    const float* bk  = (const float*)d_in[8];
    const float* wv  = (const float*)d_in[9];
    const float* bv  = (const float*)d_in[10];
    const float* wo  = (const float*)d_in[11];
    const float* bo  = (const float*)d_in[12];
    const float* iw1 = (const float*)d_in[13];
    const float* ib1 = (const float*)d_in[14];
    const float* lng = (const float*)d_in[15];
    const float* lnb = (const float*)d_in[16];
    const float* iw2 = (const float*)d_in[17];
    const float* ib2 = (const float*)d_in[18];

    float* enriched = (float*)d_out;
    float* msgs     = enriched + (size_t)BB * NN * OBSD;

    float* wsf = (float*)d_ws;
    unsigned short* wsu = (unsigned short*)(wsf + 41472);
    unsigned short* ew1s  = wsu;
    unsigned short* wcats = wsu + 16384;
    unsigned short* iw1ts = wsu + 49152;
    unsigned short* wfs   = wsu + 81920;
    unsigned short* iw2s  = wsu + 98304;

    const float* bcat  = wsf + 40960;
    const float* bfold = wsf + 41216;

    k_prep1<<<162, 256, 0, stream>>>(ew2, eb2, wq, bq, wk, bk, wv, bv,
                                     wo, bo, iw1, ib1, wsf);
    k_prep2<<<256, 512, 0, stream>>>(ew1, ew2, iw1, iw2, wsf, wsu);
    k_fused<<<BB, 512, 0, stream>>>(obs, ew1s, eb1, wcats, bcat, msgs,
                                    iw1ts, wfs, bfold, lng, lnb, iw2s, ib2,
                                    enriched);
}

// Round 10
// 165.275 us; speedup vs baseline: 1.2746x; 1.2746x over previous
//
#include <hip/hip_runtime.h>
#include <math.h>

#define BB    512
#define NN    128
#define OBSD  128
#define MSGD  64
#define EHID  128
#define IHID  256

typedef __attribute__((ext_vector_type(8))) short          s16x8;
typedef __attribute__((ext_vector_type(4))) short          s16x4;
typedef __attribute__((ext_vector_type(8))) unsigned short u16x8;
typedef __attribute__((ext_vector_type(4))) unsigned short u16x4;
typedef __attribute__((ext_vector_type(4))) float          f32x4;

// native bf16 convert -> compiler emits packed v_cvt_pk_bf16_f32 (RNE)
__device__ __forceinline__ unsigned short f2bf(float f) {
    return __builtin_bit_cast(unsigned short, (__bf16)f);
}
__device__ __forceinline__ float bf2f(unsigned short b) {
    return (float)__builtin_bit_cast(__bf16, b);
}

#if defined(__has_builtin) && __has_builtin(__builtin_amdgcn_mfma_f32_16x16x16bf16_1k)
__device__ __forceinline__ f32x4 MFMA16(s16x4 a, s16x4 b, f32x4 c) {
    return __builtin_amdgcn_mfma_f32_16x16x16bf16_1k(a, b, c, 0, 0, 0);
}
#else
__device__ __forceinline__ f32x4 MFMA16(s16x4 a, s16x4 b, f32x4 c) {
    f32x4 d;
    asm volatile("v_mfma_f32_16x16x16_bf16 %0, %1, %2, %3\n\ts_nop 7\n\ts_nop 7"
                 : "=v"(d) : "v"(a), "v"(b), "v"(c));
    return d;
}
#endif

// ---------------------------------------------------------------------------
// prep1: fold linear layers (fp32). ws fp32 layout:
//   WqP@0, WkP@8192, WvP@16384, WfP@24576, bcat@40960, bfold@41216
// ---------------------------------------------------------------------------
__global__ __launch_bounds__(256) void k_prep1(
    const float* __restrict__ ew2, const float* __restrict__ eb2,
    const float* __restrict__ wq, const float* __restrict__ bq,
    const float* __restrict__ wk, const float* __restrict__ bk,
    const float* __restrict__ wv, const float* __restrict__ bv,
    const float* __restrict__ wo, const float* __restrict__ bo,
    const float* __restrict__ iw1, const float* __restrict__ ib1,
    float* __restrict__ wsf)
{
    int idx = blockIdx.x * 256 + threadIdx.x;
    if (idx >= 41472) return;
    if (idx < 24576) {
        const float* W = (idx < 8192) ? wq : (idx < 16384) ? wk : wv;
        int t = idx & 8191;
        int k = t >> 6, n = t & 63;
        float s = 0.0f;
        for (int m = 0; m < 64; ++m) s = fmaf(ew2[k * 64 + m], W[m * 64 + n], s);
        wsf[idx] = s;
    } else if (idx < 40960) {
        int t = idx - 24576;
        int k = t >> 8, n = t & 255;
        float s = 0.0f;
        for (int m = 0; m < 64; ++m) s = fmaf(wo[k * 64 + m], iw1[(128 + m) * 256 + n], s);
        wsf[idx] = s;
    } else if (idx < 41216) {
        int n = idx - 40960;
        float s;
        if (n < 64) s = eb2[n];
        else {
            int c = n & 63;
            const float* W = (n < 128) ? wq : (n < 192) ? wk : wv;
            const float* bb = (n < 128) ? bq : (n < 192) ? bk : bv;
            s = bb[c];
            for (int m = 0; m < 64; ++m) s = fmaf(eb2[m], W[m * 64 + c], s);
        }
        wsf[idx] = s;
    } else {
        int n = idx - 41216;
        float s = ib1[n];
        for (int m = 0; m < 64; ++m) s = fmaf(bo[m], iw1[(128 + m) * 256 + n], s);
        wsf[idx] = s;
    }
}

// ---------------------------------------------------------------------------
// prep2: swizzle weights into bf16 MFMA fragment-linear layout.
// frag[((kk*NT + nt)*64 + lane)*8 + j] = bf16(W[kk*32+(lane>>4)*8+j][nt*16+(lane&15)])
// ushort layout: ew1s@0(16384) wcats@16384(32768) iw1ts@49152(32768)
//   wfs@81920(16384) iw2s@98304(32768)
// ---------------------------------------------------------------------------
__global__ __launch_bounds__(512) void k_prep2(
    const float* __restrict__ ew1, const float* __restrict__ ew2,
    const float* __restrict__ iw1, const float* __restrict__ iw2,
    const float* __restrict__ wsf, unsigned short* __restrict__ wsu)
{
    int b = blockIdx.x, t = threadIdx.x;
    int l = t >> 3, j = t & 7;
    int c = l & 15, g = l >> 4;
    float v;
    unsigned short* dst;
    if (b < 32) {              // ew1s: K=128 N=128, NT=8
        int kk = b >> 3, nt = b & 7;
        int k = kk * 32 + g * 8 + j, n = nt * 16 + c;
        v = ew1[k * 128 + n];
        dst = wsu + b * 512;
    } else if (b < 96) {       // wcats: K=128 N=256 (ew2 | WqP | WkP | WvP)
        int tt = b - 32;
        int kk = tt >> 4, nt = tt & 15;
        int k = kk * 32 + g * 8 + j, n = nt * 16 + c;
        if (n < 64)       v = ew2[k * 64 + n];
        else if (n < 128) v = wsf[0     + k * 64 + (n - 64)];
        else if (n < 192) v = wsf[8192  + k * 64 + (n - 128)];
        else              v = wsf[16384 + k * 64 + (n - 192)];
        dst = wsu + 16384 + tt * 512;
    } else if (b < 160) {      // iw1ts: K=128 N=256 (top rows of iw1)
        int tt = b - 96;
        int kk = tt >> 4, nt = tt & 15;
        int k = kk * 32 + g * 8 + j, n = nt * 16 + c;
        v = iw1[k * 256 + n];
        dst = wsu + 49152 + tt * 512;
    } else if (b < 192) {      // wfs: K=64 N=256 (WfP)
        int tt = b - 160;
        int kk = tt >> 4, nt = tt & 15;
        int k = kk * 32 + g * 8 + j, n = nt * 16 + c;
        v = wsf[24576 + k * 256 + n];
        dst = wsu + 81920 + tt * 512;
    } else {                   // iw2s: K=256 N=128
        int tt = b - 192;
        int kk = tt >> 3, nt = tt & 7;
        int k = kk * 32 + g * 8 + j, n = nt * 16 + c;
        v = iw2[k * 128 + n];
        dst = wsu + 98304 + tt * 512;
    }
    dst[l * 8 + j] = f2bf(v);
}

// ---------------------------------------------------------------------------
// k_fused v3 (round-7 structure + native cvt + staged obsE for phase E):
// one block = one batch (128 tokens), 512 threads = 8 waves (2M x 4N).
//   A: stage obs coalesced -> obsA
//   B: hid = relu(obs@ew1+eb1)           (A-frags from obsA LDS)
//   C: [msgs|q|k|vT] = hid@wcat + bcat   (msgs->global; q/k/vT overwrite arena)
//   D: attention -> ctxA; in the same barrier window re-stage obs -> obsE
//   E: integrator GEMM1 (obsE LDS + ctxA LDS) + LN partials
//   F: LN apply -> hid2;  G: out = hid2@iw2 + ib2
// Arena U (ushort idx): obsA@0 s136 | hid@17408 s136 | q@0 s68 k@8704 s68
//   vT@17408 s132 | ctxA@0 s72, obsE@17408 s136 | hid2@0 s264
// LDS 69632 + part 4096 = 73728 B -> 2 blocks/CU.
// ---------------------------------------------------------------------------
__global__ __launch_bounds__(512, 4) void k_fused(
    const float* __restrict__ obs,
    const unsigned short* __restrict__ ew1s, const float* __restrict__ eb1,
    const unsigned short* __restrict__ wcats, const float* __restrict__ bcat,
    float* __restrict__ msgs_out,
    const unsigned short* __restrict__ iw1ts, const unsigned short* __restrict__ wfs,
    const float* __restrict__ bfold, const float* __restrict__ lng,
    const float* __restrict__ lnb, const unsigned short* __restrict__ iw2s,
    const float* __restrict__ ib2, float* __restrict__ out)
{
    __shared__ unsigned short U[34816];
    __shared__ float part[128][8];

    const int tid = threadIdx.x, lane = tid & 63, w = tid >> 6;
    const int wm = w >> 2, wn = w & 3;           // M-half / N-quarter
    const int c15 = lane & 15, grp = lane >> 4;
    const long tok0 = (long)blockIdx.x * 128;
    const f32x4 zero = {0.f, 0.f, 0.f, 0.f};
    const float4* obs4 = (const float4*)(obs + tok0 * OBSD);

    // ---- A: stage obs (128x128 fp32 -> bf16), coalesced float4
    #pragma unroll
    for (int i = 0; i < 8; ++i) {
        int f = tid + i * 512;
        int t = f >> 5, kq = (f & 31) << 2;
        float4 v4 = obs4[f];
        u16x4 o;
        o[0] = f2bf(v4.x); o[1] = f2bf(v4.y); o[2] = f2bf(v4.z); o[3] = f2bf(v4.w);
        *(u16x4*)&U[t * 136 + kq] = o;
    }
    __syncthreads();                                               // 1

    // ---- B: enc GEMM1: hid = relu(obs@ew1+eb1); wave: M-half wm, nt {2wn,2wn+1}
    {
        f32x4 a1[4][2];
        #pragma unroll
        for (int m = 0; m < 4; ++m) { a1[m][0] = zero; a1[m][1] = zero; }
        #pragma unroll
        for (int kk = 0; kk < 4; ++kk) {
            s16x8 b0 = *(const s16x8*)&ew1s[(((kk << 3) + 2 * wn + 0) * 64 + lane) * 8];
            s16x8 b1 = *(const s16x8*)&ew1s[(((kk << 3) + 2 * wn + 1) * 64 + lane) * 8];
            #pragma unroll
            for (int m = 0; m < 4; ++m) {
                s16x8 a = *(const s16x8*)&U[(wm * 64 + m * 16 + c15) * 136 + kk * 32 + grp * 8];
                a1[m][0] = __builtin_amdgcn_mfma_f32_16x16x32_bf16(a, b0, a1[m][0], 0, 0, 0);
                a1[m][1] = __builtin_amdgcn_mfma_f32_16x16x32_bf16(a, b1, a1[m][1], 0, 0, 0);
            }
        }
        #pragma unroll
        for (int ntl = 0; ntl < 2; ++ntl) {
            int col = (2 * wn + ntl) * 16 + c15;
            float bias = eb1[col];
            #pragma unroll
            for (int m = 0; m < 4; ++m)
                #pragma unroll
                for (int r = 0; r < 4; ++r)
                    U[17408 + (wm * 64 + m * 16 + grp * 4 + r) * 136 + col] =
                        f2bf(fmaxf(a1[m][ntl][r] + bias, 0.f));
        }
    }
    __syncthreads();                                               // 2

    // ---- C: enc GEMM2: [msgs|q|k|v] = hid@wcat+bcat; wave owns N-quarter wn
    {
        f32x4 a2[4][4];
        #pragma unroll
        for (int m = 0; m < 4; ++m)
            #pragma unroll
            for (int n = 0; n < 4; ++n) a2[m][n] = zero;
        #pragma unroll
        for (int kk = 0; kk < 4; ++kk) {
            s16x8 b[4];
            #pragma unroll
            for (int ntl = 0; ntl < 4; ++ntl)
                b[ntl] = *(const s16x8*)&wcats[(((kk << 4) + 4 * wn + ntl) * 64 + lane) * 8];
            #pragma unroll
            for (int m = 0; m < 4; ++m) {
                s16x8 a = *(const s16x8*)&U[17408 + (wm * 64 + m * 16 + c15) * 136 + kk * 32 + grp * 8];
                #pragma unroll
                for (int ntl = 0; ntl < 4; ++ntl)
                    a2[m][ntl] = __builtin_amdgcn_mfma_f32_16x16x32_bf16(a, b[ntl], a2[m][ntl], 0, 0, 0);
            }
        }
        __syncthreads();                                           // 3 (obsA+hid dead)

        // wn==0 -> msgs (fp32 global); wn==1 -> q@0 s68; wn==2 -> k@8704 s68; wn==3 -> vT@17408 s132
        #pragma unroll
        for (int ntl = 0; ntl < 4; ++ntl) {
            int lc = ntl * 16 + c15;
            float bias = bcat[wn * 64 + lc];
            #pragma unroll
            for (int m = 0; m < 4; ++m) {
                if (wn == 3) {
                    u16x4 o;
                    #pragma unroll
                    for (int r = 0; r < 4; ++r) o[r] = f2bf(a2[m][ntl][r] + bias);
                    *(u16x4*)&U[17408 + lc * 132 + wm * 64 + m * 16 + grp * 4] = o;
                } else {
                    #pragma unroll
                    for (int r = 0; r < 4; ++r) {
                        int t = wm * 64 + m * 16 + grp * 4 + r;
                        float v = a2[m][ntl][r] + bias;
                        if (wn == 0)      msgs_out[(tok0 + t) * MSGD + lc] = v;
                        else if (wn == 1) U[t * 68 + lc] = f2bf(v);
                        else              U[8704 + t * 68 + lc] = f2bf(v);
                    }
                }
            }
        }
    }
    __syncthreads();                                               // 4

    // ---- D: attention; wave = (query-half wm, head wn)
    {
        s16x4 akf[8], avf[8];
        #pragma unroll
        for (int kt = 0; kt < 8; ++kt) {
            akf[kt] = *(const s16x4*)&U[8704 + (kt * 16 + c15) * 68 + wn * 16 + grp * 4];
            avf[kt] = *(const s16x4*)&U[17408 + (wn * 16 + c15) * 132 + kt * 16 + grp * 4];
        }
        f32x4 oacc[4];
        float il[4];
        #pragma unroll
        for (int qt = 0; qt < 4; ++qt) {
            s16x4 qf = *(const s16x4*)&U[(wm * 64 + qt * 16 + c15) * 68 + wn * 16 + grp * 4];
            f32x4 s8[8];
            #pragma unroll
            for (int kt = 0; kt < 8; ++kt) s8[kt] = MFMA16(akf[kt], qf, zero);
            float mx = -1e30f;
            #pragma unroll
            for (int kt = 0; kt < 8; ++kt)
                #pragma unroll
                for (int r = 0; r < 4; ++r) mx = fmaxf(mx, s8[kt][r]);
            mx = fmaxf(mx, __shfl_xor(mx, 16, 64));
            mx = fmaxf(mx, __shfl_xor(mx, 32, 64));
            float l = 0.f;
            #pragma unroll
            for (int kt = 0; kt < 8; ++kt)
                #pragma unroll
                for (int r = 0; r < 4; ++r) {
                    float e = __expf((s8[kt][r] - mx) * 0.25f);
                    s8[kt][r] = e;
                    l += e;
                }
            l += __shfl_xor(l, 16, 64);
            l += __shfl_xor(l, 32, 64);
            il[qt] = 1.0f / l;
            oacc[qt] = zero;
            #pragma unroll
            for (int kt = 0; kt < 8; ++kt) {
                s16x4 pb;
                #pragma unroll
                for (int r = 0; r < 4; ++r) pb[r] = (short)f2bf(s8[kt][r]);
                oacc[qt] = MFMA16(avf[kt], pb, oacc[qt]);
            }
        }
        __syncthreads();                                           // 5 (q/k/vT dead)

        // ctxA stores + obsE re-stage share this barrier window (disjoint regions)
        #pragma unroll
        for (int qt = 0; qt < 4; ++qt) {
            u16x4 o;
            #pragma unroll
            for (int r = 0; r < 4; ++r) o[r] = f2bf(oacc[qt][r] * il[qt]);
            *(u16x4*)&U[(wm * 64 + qt * 16 + c15) * 72 + wn * 16 + grp * 4] = o;
        }
        #pragma unroll
        for (int i = 0; i < 8; ++i) {
            int f = tid + i * 512;
            int t = f >> 5, kq = (f & 31) << 2;
            float4 v4 = obs4[f];
            u16x4 o;
            o[0] = f2bf(v4.x); o[1] = f2bf(v4.y); o[2] = f2bf(v4.z); o[3] = f2bf(v4.w);
            *(u16x4*)&U[17408 + t * 136 + kq] = o;
        }
    }
    __syncthreads();                                               // 6

    // ---- E: integrator GEMM1 (obsE LDS + ctxA LDS) + LN partials
    f32x4 ai[4][4];
    {
        #pragma unroll
        for (int m = 0; m < 4; ++m)
            #pragma unroll
            for (int n = 0; n < 4; ++n) ai[m][n] = zero;
        #pragma unroll
        for (int kk = 0; kk < 4; ++kk) {
            s16x8 b[4];
            #pragma unroll
            for (int ntl = 0; ntl < 4; ++ntl)
                b[ntl] = *(const s16x8*)&iw1ts[(((kk << 4) + 4 * wn + ntl) * 64 + lane) * 8];
            #pragma unroll
            for (int m = 0; m < 4; ++m) {
                s16x8 a = *(const s16x8*)&U[17408 + (wm * 64 + m * 16 + c15) * 136 + kk * 32 + grp * 8];
                #pragma unroll
                for (int ntl = 0; ntl < 4; ++ntl)
                    ai[m][ntl] = __builtin_amdgcn_mfma_f32_16x16x32_bf16(a, b[ntl], ai[m][ntl], 0, 0, 0);
            }
        }
        #pragma unroll
        for (int kk = 0; kk < 2; ++kk) {
            s16x8 b[4];
            #pragma unroll
            for (int ntl = 0; ntl < 4; ++ntl)
                b[ntl] = *(const s16x8*)&wfs[(((kk << 4) + 4 * wn + ntl) * 64 + lane) * 8];
            #pragma unroll
            for (int m = 0; m < 4; ++m) {
                s16x8 a = *(const s16x8*)&U[(wm * 64 + m * 16 + c15) * 72 + kk * 32 + grp * 8];
                #pragma unroll
                for (int ntl = 0; ntl < 4; ++ntl)
                    ai[m][ntl] = __builtin_amdgcn_mfma_f32_16x16x32_bf16(a, b[ntl], ai[m][ntl], 0, 0, 0);
            }
        }

        float bias[4];
        #pragma unroll
        for (int ntl = 0; ntl < 4; ++ntl) bias[ntl] = bfold[(4 * wn + ntl) * 16 + c15];
        #pragma unroll
        for (int m = 0; m < 4; ++m) {
            #pragma unroll
            for (int r = 0; r < 4; ++r) {
                float s = 0.f, s2 = 0.f;
                #pragma unroll
                for (int ntl = 0; ntl < 4; ++ntl) {
                    float v = ai[m][ntl][r] + bias[ntl];
                    ai[m][ntl][r] = v;
                    s += v;
                    s2 = fmaf(v, v, s2);
                }
                #pragma unroll
                for (int msk = 1; msk < 16; msk <<= 1) {
                    s  += __shfl_xor(s,  msk, 64);
                    s2 += __shfl_xor(s2, msk, 64);
                }
                if (c15 == 0)
                    *(float2*)&part[wm * 64 + m * 16 + grp * 4 + r][2 * wn] = make_float2(s, s2);
            }
        }
    }
    __syncthreads();                                               // 7 (ctxA+obsE reads done)

    if (tid < 128) {
        float4 p0 = *(const float4*)&part[tid][0];
        float4 p1 = *(const float4*)&part[tid][4];
        float s  = p0.x + p0.z + p1.x + p1.z;
        float s2 = p0.y + p0.w + p1.y + p1.w;
        float mu = s * (1.0f / IHID);
        float var = s2 * (1.0f / IHID) - mu * mu;
        *(float2*)&part[tid][0] = make_float2(mu, rsqrtf(var + 1e-5f));
    }
    __syncthreads();                                               // 8

    // ---- F: apply LN + relu -> hid2 @U[0] stride 264
    {
        float gg[4], bb[4];
        #pragma unroll
        for (int ntl = 0; ntl < 4; ++ntl) {
            int col = (4 * wn + ntl) * 16 + c15;
            gg[ntl] = lng[col];
            bb[ntl] = lnb[col];
        }
        #pragma unroll
        for (int m = 0; m < 4; ++m)
            #pragma unroll
            for (int r = 0; r < 4; ++r) {
                int t = wm * 64 + m * 16 + grp * 4 + r;
                float2 mr = *(const float2*)&part[t][0];
                #pragma unroll
                for (int ntl = 0; ntl < 4; ++ntl) {
                    float v = fmaf((ai[m][ntl][r] - mr.x) * mr.y, gg[ntl], bb[ntl]);
                    U[t * 264 + (4 * wn + ntl) * 16 + c15] = f2bf(fmaxf(v, 0.f));
                }
            }
    }
    __syncthreads();                                               // 9

    // ---- G: integrator GEMM2: out = hid2@iw2 + ib2; K=256, nt {2wn,2wn+1}
    {
        f32x4 a3[4][2];
        #pragma unroll
        for (int m = 0; m < 4; ++m) { a3[m][0] = zero; a3[m][1] = zero; }
        #pragma unroll
        for (int kk = 0; kk < 8; ++kk) {
            s16x8 b0 = *(const s16x8*)&iw2s[(((kk << 3) + 2 * wn + 0) * 64 + lane) * 8];
            s16x8 b1 = *(const s16x8*)&iw2s[(((kk << 3) + 2 * wn + 1) * 64 + lane) * 8];
            #pragma unroll
            for (int m = 0; m < 4; ++m) {
                s16x8 a = *(const s16x8*)&U[(wm * 64 + m * 16 + c15) * 264 + kk * 32 + grp * 8];
                a3[m][0] = __builtin_amdgcn_mfma_f32_16x16x32_bf16(a, b0, a3[m][0], 0, 0, 0);
                a3[m][1] = __builtin_amdgcn_mfma_f32_16x16x32_bf16(a, b1, a3[m][1], 0, 0, 0);
            }
        }
        #pragma unroll
        for (int ntl = 0; ntl < 2; ++ntl) {
            int col = (2 * wn + ntl) * 16 + c15;
            float bias2 = ib2[col];
            #pragma unroll
            for (int m = 0; m < 4; ++m)
                #pragma unroll
                for (int r = 0; r < 4; ++r)
                    out[(tok0 + wm * 64 + m * 16 + grp * 4 + r) * OBSD + col] =
                        a3[m][ntl][r] + bias2;
        }
    }
}

// ---------------------------------------------------------------------------
extern "C" void kernel_launch(void* const* d_in, const int* in_sizes, int n_in,
                              void* d_out, int out_size, void* d_ws, size_t ws_size,
                              hipStream_t stream)
{
    (void)in_sizes; (void)n_in; (void)out_size; (void)ws_size;

    const float* obs = (const float*)d_in[0];
    const float* ew1 = (const float*)d_in[1];
    const float* eb1 = (const float*)d_in[2];
    const float* ew2 = (const float*)d_in[3];
    const float* eb2 = (const float*)d_in[4];
    const float* wq  = (const float*)d_in[5];
    const float* bq  = (const float*)d_in[6];
    const float* wk  = (const float*)d_in[7];
    const float* bk  = (const float*)d_in[8];
    const float* wv  = (const float*)d_in[9];
    const float* bv  = (const float*)d_in[10];
    const float* wo  = (const float*)d_in[11];
    const float* bo  = (const float*)d_in[12];
    const float* iw1 = (const float*)d_in[13];
    const float* ib1 = (const float*)d_in[14];
    const float* lng = (const float*)d_in[15];
    const float* lnb = (const float*)d_in[16];
    const float* iw2 = (const float*)d_in[17];
    const float* ib2 = (const float*)d_in[18];

    float* enriched = (float*)d_out;
    float* msgs     = enriched + (size_t)BB * NN * OBSD;

    float* wsf = (float*)d_ws;
    unsigned short* wsu = (unsigned short*)(wsf + 41472);
    unsigned short* ew1s  = wsu;
    unsigned short* wcats = wsu + 16384;
    unsigned short* iw1ts = wsu + 49152;
    unsigned short* wfs   = wsu + 81920;
    unsigned short* iw2s  = wsu + 98304;

    const float* bcat  = wsf + 40960;
    const float* bfold = wsf + 41216;

    k_prep1<<<162, 256, 0, stream>>>(ew2, eb2, wq, bq, wk, bk, wv, bv,
                                     wo, bo, iw1, ib1, wsf);
    k_prep2<<<256, 512, 0, stream>>>(ew1, ew2, iw1, iw2, wsf, wsu);
    k_fused<<<BB, 512, 0, stream>>>(obs, ew1s, eb1, wcats, bcat, msgs,
                                    iw1ts, wfs, bfold, lng, lnb, iw2s, ib2,
                                    enriched);
}